// Round 4
// baseline (702.917 us; speedup 1.0000x reference)
//
#include <hip/hip_runtime.h>

// ---------------------------------------------------------------------------
// RCSM engine, MI355X/gfx950.  Inputs/outputs are FP32 (reference dtypes).
// Internal: fp32 math; the two big projections run on
// v_mfma_f32_16x16x32_bf16 with bf16-converted operands (ternary weights +
// hidden), error << the 2% absmax threshold.  force_depth fixed at 2.
// Workspace ~5.7 MB; reason ping-pong staged inside d_out (in-place-safe).
// ---------------------------------------------------------------------------

#define DR   128
#define DM   1024
#define NTOK 16384
#define NOPS 32

typedef __attribute__((ext_vector_type(8))) short bfrag;   // 8 x bf16 bits
typedef __attribute__((ext_vector_type(4))) float f32x4;

__device__ __forceinline__ ushort f2b_bits(float f) {
  union { float f; uint i; } c; c.f = f;
  uint x = c.i;
  return (ushort)((x + 0x7fffu + ((x >> 16) & 1u)) >> 16);   // RNE
}
__device__ __forceinline__ float qeff(float w, float s) {
  float q = rintf(w / s);                 // round-half-even, matches jnp.round
  q = fminf(1.f, fmaxf(-1.f, q));
  return q * s;
}
__device__ __forceinline__ float waveRed(float v) {
#pragma unroll
  for (int m = 32; m > 0; m >>= 1) v += __shfl_xor(v, m, 64);
  return v;
}

// ---------------- workspace layout (bytes; total ~5.7 MB) ------------------
#define OFF_SUMS    0                        // 64 f32
#define OFF_OPSSC   256                      // 32 f32 per-op scales
#define OFF_WDE     512                      // bf16 [128][1024]
#define OFF_WUE     (OFF_WDE + 262144)       // bf16 [1024][128]
#define OFF_WRT     (OFF_WUE + 262144)       // f32  [128][32]
#define OFF_OPST    (OFF_WRT + 16384)        // int8 [32][128(d)][128(o)]
#define OFF_WSUMT   (OFF_OPST + 524288)      // f32  [128(d)][128(o)]
#define OFF_WREADT  (OFF_WSUMT + 65536)
#define OFF_WWKT    (OFF_WREADT + 65536)
#define OFF_WWVT    (OFF_WWKT + 65536)
#define OFF_WMIXAT  (OFF_WWVT + 65536)
#define OFF_WMIXBT  (OFF_WMIXAT + 65536)
#define OFF_SLOTSF  (OFF_WMIXBT + 65536)     // f32 [16][128]
#define OFF_WWG     (OFF_SLOTSF + 8192)      // f32 [128]
#define OFF_GAMMAF  (OFF_WWG + 512)
#define OFF_BETAF   (OFF_GAMMAF + 512)
#define OFF_WSCALEF (OFF_BETAF + 512)
#define OFF_RWS     (OFF_WSCALEF + 256)      // bf16 [16384][128]  (4 MB)
#define WS_TOTAL    (OFF_RWS + 4194304)

// --------------------------- scale reductions ------------------------------
__global__ __launch_bounds__(256) void k_absum(const float* __restrict__ w, int n,
                                               float* __restrict__ out) {
  __shared__ float ws4[4];
  float s = 0.f;
  for (int i = blockIdx.x * 256 + threadIdx.x; i < n; i += gridDim.x * 256)
    s += fabsf(w[i]);
  s = waveRed(s);
  int lane = threadIdx.x & 63, wv = threadIdx.x >> 6;
  if (lane == 0) ws4[wv] = s;
  __syncthreads();
  if (threadIdx.x == 0) atomicAdd(out, ws4[0] + ws4[1] + ws4[2] + ws4[3]);
}

__global__ __launch_bounds__(256) void k_absum_ops(const float* __restrict__ ops,
                                                   float* __restrict__ outs) {
  __shared__ float ws4[4];
  const int n = blockIdx.y;
  const float* w = ops + (size_t)n * (DR * DR);
  float s = 0.f;
  for (int i = blockIdx.x * 256 + threadIdx.x; i < DR * DR; i += gridDim.x * 256)
    s += fabsf(w[i]);
  s = waveRed(s);
  int lane = threadIdx.x & 63, wv = threadIdx.x >> 6;
  if (lane == 0) ws4[wv] = s;
  __syncthreads();
  if (threadIdx.x == 0) atomicAdd(&outs[n], ws4[0] + ws4[1] + ws4[2] + ws4[3]);
}

// --------------------------- weight build ----------------------------------
__global__ __launch_bounds__(256) void k_build(
    const float* __restrict__ W_down, const float* __restrict__ W_up,
    const float* __restrict__ W_router, const float* __restrict__ ops,
    const float* __restrict__ W_read, const float* __restrict__ W_wk,
    const float* __restrict__ W_wg, const float* __restrict__ W_wv,
    const float* __restrict__ W_mix, const float* __restrict__ slots,
    const float* __restrict__ gamma, const float* __restrict__ beta,
    const float* __restrict__ wscale, int has_wsc, const float* __restrict__ sums,
    ushort* __restrict__ WdE, ushort* __restrict__ WuE, float* __restrict__ WrT,
    char* __restrict__ opsT, float* __restrict__ opsScale,
    float* __restrict__ WsumT, float* __restrict__ WreadT,
    float* __restrict__ WwkT, float* __restrict__ WwvT, float* __restrict__ WwgF,
    float* __restrict__ WmixAT, float* __restrict__ WmixBT, float* __restrict__ slotsF,
    float* __restrict__ gammaF, float* __restrict__ betaF, float* __restrict__ wscF) {
  int id = blockIdx.x * 256 + threadIdx.x;
  const float s_wd = fmaxf(sums[0] * (1.f / 131072.f), 1e-5f);
  const float s_wr = fmaxf(sums[1] * (1.f / 4096.f), 1e-5f);
  const float s_wu = fmaxf(sums[2] * (1.f / 131072.f), 1e-5f);

  if (id < 131072) { WdE[id] = f2b_bits(qeff(W_down[id], s_wd)); return; }
  id -= 131072;
  if (id < 131072) { WuE[id] = f2b_bits(qeff(W_up[id], s_wu)); return; }
  id -= 131072;
  if (id < 4096) {              // WrT[d][n] = qeff(W_router[n][d])
    int d = id >> 5, n = id & 31;
    WrT[id] = qeff(W_router[n * DR + d], s_wr);
    return;
  }
  id -= 4096;
  if (id < 524288) {            // opsT[n][d][o] = ternary q of ops[n][o][d]
    int n = id >> 14, rem = id & 16383, d = rem >> 7, o = rem & 127;
    float s = fmaxf(sums[3 + n] * (1.f / 16384.f), 1e-5f);
    float q = rintf(ops[(size_t)n * 16384 + o * DR + d] / s);
    q = fminf(1.f, fmaxf(-1.f, q));
    opsT[id] = (char)(int)q;
    return;
  }
  id -= 524288;
  if (id < 32) { opsScale[id] = fmaxf(sums[3 + id] * (1.f / 16384.f), 1e-5f); return; }
  id -= 32;
  if (id < 16384) {             // WsumT[d][o] = sum_n qeff(ops[n][o][d])
    int d = id >> 7, o = id & 127;
    float a = 0.f;
    for (int n = 0; n < NOPS; ++n) {
      float s = fmaxf(sums[3 + n] * (1.f / 16384.f), 1e-5f);
      a += qeff(ops[(size_t)n * 16384 + o * DR + d], s);
    }
    WsumT[id] = a;
    return;
  }
  id -= 16384;
  if (id < 16384) { int d = id >> 7, o = id & 127; WreadT[id] = W_read[o * DR + d]; return; }
  id -= 16384;
  if (id < 16384) { int d = id >> 7, o = id & 127; WwkT[id] = W_wk[o * DR + d]; return; }
  id -= 16384;
  if (id < 16384) { int d = id >> 7, o = id & 127; WwvT[id] = W_wv[o * DR + d]; return; }
  id -= 16384;
  if (id < 16384) { int r = id >> 7, o = id & 127; WmixAT[id] = W_mix[o * 256 + r]; return; }
  id -= 16384;
  if (id < 16384) { int r = id >> 7, o = id & 127; WmixBT[id] = W_mix[o * 256 + 128 + r]; return; }
  id -= 16384;
  if (id < 2048) { slotsF[id] = slots[id]; return; }
  id -= 2048;
  if (id < 128) { WwgF[id] = W_wg[id]; return; }
  id -= 128;
  if (id < 128) { gammaF[id] = gamma[id]; return; }
  id -= 128;
  if (id < 128) { betaF[id] = beta[id]; return; }
  id -= 128;
  if (id == 0) { wscF[0] = has_wsc ? wscale[0] : 0.01f; }
}

// ------------------- down projection: MFMA bf16 GEMM -----------------------
// R0[t][o] (fp32) = sum_k hidden[t][k] * WdE[o][k];  M=16384 N=128 K=1024
// A operand: fp32 hidden converted to bf16 in-register.
__global__ __launch_bounds__(256) void k_down(const float* __restrict__ hidden,
                                              const ushort* __restrict__ WdE,
                                              float* __restrict__ R0) {
  const int wave = threadIdx.x >> 6, lane = threadIdx.x & 63;
  const int quad = lane >> 4, mrow = lane & 15;
  const int m0 = blockIdx.x * 64 + wave * 16;

  f32x4 acc[8];
#pragma unroll
  for (int i = 0; i < 8; ++i) acc[i] = (f32x4){0.f, 0.f, 0.f, 0.f};

  const float* Ap = hidden + (size_t)(m0 + mrow) * DM + quad * 8;
  for (int kt = 0; kt < 32; ++kt) {
    float4 a0 = *(const float4*)(Ap + kt * 32);
    float4 a1 = *(const float4*)(Ap + kt * 32 + 4);
    bfrag a;
    a[0] = (short)f2b_bits(a0.x); a[1] = (short)f2b_bits(a0.y);
    a[2] = (short)f2b_bits(a0.z); a[3] = (short)f2b_bits(a0.w);
    a[4] = (short)f2b_bits(a1.x); a[5] = (short)f2b_bits(a1.y);
    a[6] = (short)f2b_bits(a1.z); a[7] = (short)f2b_bits(a1.w);
#pragma unroll
    for (int nt = 0; nt < 8; ++nt) {
      const ushort* Bp = WdE + (size_t)(nt * 16 + mrow) * DM + kt * 32 + quad * 8;
      bfrag b = *(const bfrag*)Bp;
      acc[nt] = __builtin_amdgcn_mfma_f32_16x16x32_bf16(a, b, acc[nt], 0, 0, 0);
    }
  }
#pragma unroll
  for (int nt = 0; nt < 8; ++nt)
#pragma unroll
    for (int r = 0; r < 4; ++r)
      R0[(size_t)(m0 + quad * 4 + r) * DR + nt * 16 + mrow] = acc[nt][r];
}

// ------------------------- fused single pass -------------------------------
// Loads its 16 tokens into LDS first, writes its own 16 tokens last =>
// safe for in-place operation (Rin == Rout).
__global__ __launch_bounds__(256) void k_pass(
    const float* __restrict__ Rin, float* __restrict__ Rout,
    const float* __restrict__ WrT, const char* __restrict__ opsT,
    const float* __restrict__ opsScale,
    const float* __restrict__ WsumT, const float* __restrict__ WreadT,
    const float* __restrict__ WmixAT, const float* __restrict__ WmixBT,
    const float* __restrict__ slotsF, const float* __restrict__ gammaF,
    const float* __restrict__ betaF) {
  __shared__ float xs[16][132];
  __shared__ float Ao[16][132];
  __shared__ float Kk[16][132];
  __shared__ float lg[16][32];
  __shared__ float attn[16][16];
  __shared__ int   seli[16][2];
  __shared__ float selw[16][2];
  __shared__ float mu[16], rsd[16];

  const int tid = threadIdx.x;
  const int t0 = blockIdx.x * 16;

  {
    const float* src = Rin + (size_t)t0 * DR + tid * 8;
    float4 u0 = *(const float4*)(src);
    float4 u1 = *(const float4*)(src + 4);
    int r = tid >> 4, c = (tid & 15) * 8;
    xs[r][c + 0] = u0.x; xs[r][c + 1] = u0.y; xs[r][c + 2] = u0.z; xs[r][c + 3] = u0.w;
    xs[r][c + 4] = u1.x; xs[r][c + 5] = u1.y; xs[r][c + 6] = u1.z; xs[r][c + 7] = u1.w;
  }
  __syncthreads();

  // router logits (ternary W_router)
  for (int p = tid; p < 512; p += 256) {
    int tt2 = p >> 5, n = p & 31;
    float a = 0.f;
    for (int d = 0; d < DR; ++d) a += xs[tt2][d] * WrT[d * 32 + n];
    lg[tt2][n] = a;
  }
  __syncthreads();

  // exact top-2 (first-occurrence tie-break, matches lax.top_k), softmax of 2
  if (tid < 16) {
    float v0 = -1e30f; int i0 = 0;
#pragma unroll
    for (int n = 0; n < 32; ++n) { float v = lg[tid][n]; if (v > v0) { v0 = v; i0 = n; } }
    float v1 = -1e30f; int i1 = 0;
#pragma unroll
    for (int n = 0; n < 32; ++n) {
      if (n != i0) { float v = lg[tid][n]; if (v > v1) { v1 = v; i1 = n; } }
    }
    float e = expf(v1 - v0);
    float w0 = 1.f / (1.f + e);
    seli[tid][0] = i0; seli[tid][1] = i1;
    selw[tid][0] = w0; selw[tid][1] = e * w0;
  }
  __syncthreads();

  const int tt = tid >> 4;
  const int ob = (tid & 15) * 8;

  // all-op-sum matvec + read-key matvec
  float accA[8] = {0, 0, 0, 0, 0, 0, 0, 0};
  float accK[8] = {0, 0, 0, 0, 0, 0, 0, 0};
  for (int d = 0; d < DR; ++d) {
    float x = xs[tt][d];
    const float4 wa0 = *(const float4*)(WsumT + d * DR + ob);
    const float4 wa1 = *(const float4*)(WsumT + d * DR + ob + 4);
    const float4 wk0 = *(const float4*)(WreadT + d * DR + ob);
    const float4 wk1 = *(const float4*)(WreadT + d * DR + ob + 4);
    accA[0] += x * wa0.x; accA[1] += x * wa0.y; accA[2] += x * wa0.z; accA[3] += x * wa0.w;
    accA[4] += x * wa1.x; accA[5] += x * wa1.y; accA[6] += x * wa1.z; accA[7] += x * wa1.w;
    accK[0] += x * wk0.x; accK[1] += x * wk0.y; accK[2] += x * wk0.z; accK[3] += x * wk0.w;
    accK[4] += x * wk1.x; accK[5] += x * wk1.y; accK[6] += x * wk1.z; accK[7] += x * wk1.w;
  }
#pragma unroll
  for (int i = 0; i < 8; ++i) Kk[tt][ob + i] = accK[i];

  // gather: 2 selected ternary ops (int8 q, per-op scale folded into weight)
  float gt[8] = {0, 0, 0, 0, 0, 0, 0, 0};
#pragma unroll
  for (int kk = 0; kk < 2; ++kk) {
    const int n = seli[tt][kk];
    const float wgt = selw[tt][kk] * opsScale[n];
    const char* P = opsT + (size_t)n * (DR * DR) + ob;
    float ga[8] = {0, 0, 0, 0, 0, 0, 0, 0};
    for (int d = 0; d < DR; ++d) {
      float x = xs[tt][d];
      uint2 u = *(const uint2*)(P + (size_t)d * DR);
      ga[0] += x * (float)(char)(u.x);
      ga[1] += x * (float)(char)(u.x >> 8);
      ga[2] += x * (float)(char)(u.x >> 16);
      ga[3] += x * (float)(char)(u.x >> 24);
      ga[4] += x * (float)(char)(u.y);
      ga[5] += x * (float)(char)(u.y >> 8);
      ga[6] += x * (float)(char)(u.y >> 16);
      ga[7] += x * (float)(char)(u.y >> 24);
    }
#pragma unroll
    for (int i = 0; i < 8; ++i) gt[i] += wgt * ga[i];
  }
  const float COEF = 1e-5f / 32.f;
#pragma unroll
  for (int i = 0; i < 8; ++i) Ao[tt][ob + i] = accA[i] * COEF + gt[i];
  __syncthreads();

  // slot attention scores
  {
    int st = tid >> 4, j = tid & 15;
    float a = 0.f;
    for (int o = 0; o < DR; ++o) a += Kk[st][o] * slotsF[j * DR + o];
    attn[st][j] = a * 0.088388347648318447f;   // 1/sqrt(128)
  }
  __syncthreads();
  if (tid < 16) {
    float m = -1e30f;
#pragma unroll
    for (int j = 0; j < 16; ++j) m = fmaxf(m, attn[tid][j]);
    float s = 0.f;
#pragma unroll
    for (int j = 0; j < 16; ++j) { float e = expf(attn[tid][j] - m); attn[tid][j] = e; s += e; }
    float inv = 1.f / s;
#pragma unroll
    for (int j = 0; j < 16; ++j) attn[tid][j] *= inv;
  }
  __syncthreads();

  // mem_out = attn @ slots  (overwrites Kk; key fully consumed above)
  {
    float m[8] = {0, 0, 0, 0, 0, 0, 0, 0};
#pragma unroll
    for (int j = 0; j < 16; ++j) {
      float aj = attn[tt][j];
      const float4 s0 = *(const float4*)(slotsF + j * DR + ob);
      const float4 s1 = *(const float4*)(slotsF + j * DR + ob + 4);
      m[0] += aj * s0.x; m[1] += aj * s0.y; m[2] += aj * s0.z; m[3] += aj * s0.w;
      m[4] += aj * s1.x; m[5] += aj * s1.y; m[6] += aj * s1.z; m[7] += aj * s1.w;
    }
#pragma unroll
    for (int i = 0; i < 8; ++i) Kk[tt][ob + i] = m[i];
  }
  __syncthreads();

  // mixed = [op_out, mem_out] @ W_mix^T + residual; write back into xs
  {
    float y[8];
#pragma unroll
    for (int i = 0; i < 8; ++i) y[i] = xs[tt][ob + i];
    for (int d = 0; d < DR; ++d) {
      float av = Ao[tt][d];
      float kv = Kk[tt][d];
      const float4 wa0 = *(const float4*)(WmixAT + d * DR + ob);
      const float4 wa1 = *(const float4*)(WmixAT + d * DR + ob + 4);
      const float4 wb0 = *(const float4*)(WmixBT + d * DR + ob);
      const float4 wb1 = *(const float4*)(WmixBT + d * DR + ob + 4);
      y[0] += av * wa0.x + kv * wb0.x; y[1] += av * wa0.y + kv * wb0.y;
      y[2] += av * wa0.z + kv * wb0.z; y[3] += av * wa0.w + kv * wb0.w;
      y[4] += av * wa1.x + kv * wb1.x; y[5] += av * wa1.y + kv * wb1.y;
      y[6] += av * wa1.z + kv * wb1.z; y[7] += av * wa1.w + kv * wb1.w;
    }
#pragma unroll
    for (int i = 0; i < 8; ++i) xs[tt][ob + i] = y[i];
  }
  __syncthreads();

  if (tid < 16) {
    float s = 0.f;
    for (int o = 0; o < DR; ++o) s += xs[tid][o];
    float m = s * (1.f / DR);
    float v = 0.f;
    for (int o = 0; o < DR; ++o) { float d = xs[tid][o] - m; v += d * d; }
    mu[tid] = m;
    rsd[tid] = rsqrtf(v * (1.f / DR) + 1e-5f);
  }
  __syncthreads();

  for (int i = tid; i < 2048; i += 256) {
    int r = i >> 7, o = i & 127;
    Rout[(size_t)t0 * DR + i] = (xs[r][o] - mu[r]) * rsd[r] * gammaF[o] + betaF[o];
  }
}

// -------- write signal: fp32 reason in -> bf16 final reason out ------------
__global__ __launch_bounds__(256) void k_write(
    const float* __restrict__ Rin, ushort* __restrict__ Rf,
    const float* __restrict__ WwkT, const float* __restrict__ WwvT,
    const float* __restrict__ WwgF, const float* __restrict__ slotsF,
    const float* __restrict__ wscF) {
  __shared__ float xs[16][132];
  __shared__ float Kw[16][132];
  __shared__ float attn[16][16];
  __shared__ float wgv[16];

  const int tid = threadIdx.x;
  const int t0 = blockIdx.x * 16;
  {
    const float* src = Rin + (size_t)t0 * DR + tid * 8;
    float4 u0 = *(const float4*)(src);
    float4 u1 = *(const float4*)(src + 4);
    int r = tid >> 4, c = (tid & 15) * 8;
    xs[r][c + 0] = u0.x; xs[r][c + 1] = u0.y; xs[r][c + 2] = u0.z; xs[r][c + 3] = u0.w;
    xs[r][c + 4] = u1.x; xs[r][c + 5] = u1.y; xs[r][c + 6] = u1.z; xs[r][c + 7] = u1.w;
  }
  __syncthreads();

  const int tt = tid >> 4;
  const int ob = (tid & 15) * 8;

  float accK[8] = {0, 0, 0, 0, 0, 0, 0, 0};
  float accV[8] = {0, 0, 0, 0, 0, 0, 0, 0};
  for (int d = 0; d < DR; ++d) {
    float x = xs[tt][d];
    const float4 k0 = *(const float4*)(WwkT + d * DR + ob);
    const float4 k1 = *(const float4*)(WwkT + d * DR + ob + 4);
    const float4 v0 = *(const float4*)(WwvT + d * DR + ob);
    const float4 v1 = *(const float4*)(WwvT + d * DR + ob + 4);
    accK[0] += x * k0.x; accK[1] += x * k0.y; accK[2] += x * k0.z; accK[3] += x * k0.w;
    accK[4] += x * k1.x; accK[5] += x * k1.y; accK[6] += x * k1.z; accK[7] += x * k1.w;
    accV[0] += x * v0.x; accV[1] += x * v0.y; accV[2] += x * v0.z; accV[3] += x * v0.w;
    accV[4] += x * v1.x; accV[5] += x * v1.y; accV[6] += x * v1.z; accV[7] += x * v1.w;
  }
#pragma unroll
  for (int i = 0; i < 8; ++i) Kw[tt][ob + i] = accK[i];
  if (tid < 16) {
    float z = 0.f;
    for (int d = 0; d < DR; ++d) z += xs[tid][d] * WwgF[d];
    wgv[tid] = 1.f / (1.f + expf(-z));
  }
  __syncthreads();

  {
    int st = tid >> 4, j = tid & 15;
    float a = 0.f;
    for (int o = 0; o < DR; ++o) a += Kw[st][o] * slotsF[j * DR + o];
    attn[st][j] = a * 0.088388347648318447f;
  }
  __syncthreads();
  if (tid < 16) {
    float m = -1e30f;
#pragma unroll
    for (int j = 0; j < 16; ++j) m = fmaxf(m, attn[tid][j]);
    float s = 0.f;
#pragma unroll
    for (int j = 0; j < 16; ++j) { float e = expf(attn[tid][j] - m); attn[tid][j] = e; s += e; }
    float inv = 1.f / s;
#pragma unroll
    for (int j = 0; j < 16; ++j) attn[tid][j] *= inv;
  }
  __syncthreads();

  {
    float m[8] = {0, 0, 0, 0, 0, 0, 0, 0};
#pragma unroll
    for (int j = 0; j < 16; ++j) {
      float aj = attn[tt][j];
      const float4 s0 = *(const float4*)(slotsF + j * DR + ob);
      const float4 s1 = *(const float4*)(slotsF + j * DR + ob + 4);
      m[0] += aj * s0.x; m[1] += aj * s0.y; m[2] += aj * s0.z; m[3] += aj * s0.w;
      m[4] += aj * s1.x; m[5] += aj * s1.y; m[6] += aj * s1.z; m[7] += aj * s1.w;
    }
    const float wsc = wscF[0];
    const float wg = wgv[tt];
#pragma unroll
    for (int i = 0; i < 8; ++i) {
      float r = xs[tt][ob + i] + wsc * (wg * accV[i] + 0.1f * m[i]);
      Rf[(size_t)(t0 + tt) * DR + ob + i] = f2b_bits(r);
    }
  }
}

// -------------------- up projection + residual (MFMA) ----------------------
// out[t][j] = hidden[t][j] + sum_k Rf[t][k] * WuE[j][k];  M=16384 N=1024 K=128
__global__ __launch_bounds__(256) void k_up(const ushort* __restrict__ Rf,
                                            const ushort* __restrict__ WuE,
                                            const float* __restrict__ hidden,
                                            float* __restrict__ out) {
  const int wave = threadIdx.x >> 6, lane = threadIdx.x & 63;
  const int quad = lane >> 4, mrow = lane & 15;
  const int mt = blockIdx.x >> 3, ngrp = blockIdx.x & 7;
  const int m0 = mt * 64 + wave * 16;
  const int ng = ngrp * 8;

  f32x4 acc[8];
#pragma unroll
  for (int i = 0; i < 8; ++i) acc[i] = (f32x4){0.f, 0.f, 0.f, 0.f};

  const ushort* Ap = Rf + (size_t)(m0 + mrow) * DR + quad * 8;
#pragma unroll
  for (int kt = 0; kt < 4; ++kt) {
    bfrag a = *(const bfrag*)(Ap + kt * 32);
#pragma unroll
    for (int nt = 0; nt < 8; ++nt) {
      const ushort* Bp = WuE + (size_t)((ng + nt) * 16 + mrow) * DR + kt * 32 + quad * 8;
      bfrag b = *(const bfrag*)Bp;
      acc[nt] = __builtin_amdgcn_mfma_f32_16x16x32_bf16(a, b, acc[nt], 0, 0, 0);
    }
  }
#pragma unroll
  for (int nt = 0; nt < 8; ++nt)
#pragma unroll
    for (int r = 0; r < 4; ++r) {
      const int token = m0 + quad * 4 + r;
      const int j = (ng + nt) * 16 + mrow;
      const size_t idx = (size_t)token * DM + j;
      out[idx] = hidden[idx] + acc[nt][r];
    }
}

// ---------------------------------------------------------------------------
extern "C" void kernel_launch(void* const* d_in, const int* in_sizes, int n_in,
                              void* d_out, int out_size, void* d_ws, size_t ws_size,
                              hipStream_t stream) {
  // Resolve inputs by size signature: filter out scalar (size-1) entries;
  // the 13 non-scalar inputs keep a fixed relative order.
  int ns[20]; int nn = 0; int lastsc = -1;
  for (int i = 0; i < n_in; ++i) {
    if (in_sizes[i] == 1) lastsc = i;
    else if (nn < 20) ns[nn++] = i;
  }
  int iH = 0, iWd = 2, iWu = 3, iOps = 4, iWr = 5, iSl = 6, iRe = 7,
      iWk = 8, iWg = 9, iWv = 10, iMx = 11, iG = 12, iB = 13;
  if (nn >= 13) {
    iH  = ns[0];  iWd = ns[1];  iWu = ns[2];  iOps = ns[3]; iWr = ns[4];
    iSl = ns[5];  iRe = ns[6];  iWk = ns[7];  iWg = ns[8];  iWv = ns[9];
    iMx = ns[10]; iG  = ns[11]; iB  = ns[12];
  }
  const float* hidden   = (const float*)d_in[iH];
  const float* W_down   = (const float*)d_in[iWd];
  const float* W_up     = (const float*)d_in[iWu];
  const float* opsw     = (const float*)d_in[iOps];
  const float* W_router = (const float*)d_in[iWr];
  const float* slots    = (const float*)d_in[iSl];
  const float* W_read   = (const float*)d_in[iRe];
  const float* W_wk     = (const float*)d_in[iWk];
  const float* W_wg     = (const float*)d_in[iWg];
  const float* W_wv     = (const float*)d_in[iWv];
  const float* W_mix    = (const float*)d_in[iMx];
  const float* lng      = (const float*)d_in[iG];
  const float* lnb      = (const float*)d_in[iB];
  const float* wscale   = (lastsc >= 0) ? (const float*)d_in[lastsc] : (const float*)d_in[iG];
  const int has_wsc     = (lastsc >= 0) ? 1 : 0;

  char* ws = (char*)d_ws;
  float*  sums   = (float*)(ws + OFF_SUMS);
  float*  opsSc  = (float*)(ws + OFF_OPSSC);
  ushort* WdE    = (ushort*)(ws + OFF_WDE);
  ushort* WuE    = (ushort*)(ws + OFF_WUE);
  float*  WrT    = (float*)(ws + OFF_WRT);
  char*   opsT   = (char*)(ws + OFF_OPST);
  float*  WsumT  = (float*)(ws + OFF_WSUMT);
  float*  WreadT = (float*)(ws + OFF_WREADT);
  float*  WwkT   = (float*)(ws + OFF_WWKT);
  float*  WwvT   = (float*)(ws + OFF_WWVT);
  float*  WmixAT = (float*)(ws + OFF_WMIXAT);
  float*  WmixBT = (float*)(ws + OFF_WMIXBT);
  float*  slotsF = (float*)(ws + OFF_SLOTSF);
  float*  WwgF   = (float*)(ws + OFF_WWG);
  float*  gammaF = (float*)(ws + OFF_GAMMAF);
  float*  betaF  = (float*)(ws + OFF_BETAF);
  float*  wscF   = (float*)(ws + OFF_WSCALEF);
  ushort* Rws    = (ushort*)(ws + OFF_RWS);      // bf16 [16384][128] final reason
  float*  Rlo    = (float*)d_out;                // fp32 [16384][128] staged in d_out

  hipMemsetAsync(ws + OFF_SUMS, 0, 256, stream);
  k_absum<<<128, 256, 0, stream>>>(W_down, 131072, &sums[0]);
  k_absum<<<4, 256, 0, stream>>>(W_router, 4096, &sums[1]);
  k_absum<<<128, 256, 0, stream>>>(W_up, 131072, &sums[2]);
  k_absum_ops<<<dim3(4, 32), 256, 0, stream>>>(opsw, sums + 3);
  k_build<<<3482, 256, 0, stream>>>(W_down, W_up, W_router, opsw, W_read, W_wk, W_wg,
                                    W_wv, W_mix, slots, lng, lnb, wscale, has_wsc, sums,
                                    WdE, WuE, WrT, opsT, opsSc, WsumT, WreadT, WwkT,
                                    WwvT, WwgF, WmixAT, WmixBT, slotsF, gammaF, betaF,
                                    wscF);
  k_down<<<256, 256, 0, stream>>>(hidden, WdE, Rlo);
  // passes run in-place in d_out's first 8 MB (block-self-contained)
  k_pass<<<1024, 256, 0, stream>>>(Rlo, Rlo, WrT, opsT, opsSc, WsumT, WreadT,
                                   WmixAT, WmixBT, slotsF, gammaF, betaF);
  k_pass<<<1024, 256, 0, stream>>>(Rlo, Rlo, WrT, opsT, opsSc, WsumT, WreadT,
                                   WmixAT, WmixBT, slotsF, gammaF, betaF);
  // write-signal: d_out-lo (fp32) -> ws (bf16); then k_up overwrites all d_out
  k_write<<<1024, 256, 0, stream>>>(Rlo, Rws, WwkT, WwvT, WwgF, slotsF, wscF);
  k_up<<<2048, 256, 0, stream>>>(Rws, WuE, hidden, (float*)d_out);
}

// Round 5
// 639.062 us; speedup vs baseline: 1.0999x; 1.0999x over previous
//
#include <hip/hip_runtime.h>

// ---------------------------------------------------------------------------
// RCSM engine, MI355X/gfx950.  FP32 in/out.  Round 5: GEMM-ification.
//  * op library: dense MFMA over all 32 ternary ops with per-token coef
//    (folds top-2 gather AND the 1e-5/n_ops all-op sum into one GEMM)
//  * rank-16 algebra: M_rs=W_read^T S^T, M_ws=W_wk^T S^T, SB=S W_mixB^T
//    eliminate all per-token 128x128 key/mem matvecs
//  * mix+LN and W_wv as MFMA GEMMs with in-register shuffle LN
// Scratch: big arrays staged in d_out (k_up overwrites all of it last);
// RF (final reason, bf16) lives in ws to avoid k_up read/write race.
// ---------------------------------------------------------------------------

#define DR   128
#define DM   1024
#define NTOK 16384
#define NOPS 32
#define COEF (1e-5f / 32.f)

typedef __attribute__((ext_vector_type(8))) short bfrag;   // 8 x bf16 bits
typedef __attribute__((ext_vector_type(4))) float f32x4;

__device__ __forceinline__ ushort f2b_bits(float f) {
  union { float f; uint i; } c; c.f = f;
  uint x = c.i;
  return (ushort)((x + 0x7fffu + ((x >> 16) & 1u)) >> 16);   // RNE
}
__device__ __forceinline__ float qeff(float w, float s) {
  float q = rintf(w / s);
  q = fminf(1.f, fmaxf(-1.f, q));
  return q * s;
}
__device__ __forceinline__ float waveRed(float v) {
#pragma unroll
  for (int m = 32; m > 0; m >>= 1) v += __shfl_xor(v, m, 64);
  return v;
}

// ---------------- ws layout (bytes; total ~5.9 MB) -------------------------
#define OFF_SUMS    0                        // 64 f32
#define OFF_OPSSC   256                      // 32 f32
#define OFF_WDE     512                      // bf16 [128][1024]
#define OFF_WUE     (OFF_WDE + 262144)       // bf16 [1024][128]
#define OFF_WRT     (OFF_WUE + 262144)       // f32  [128(d)][32(n)]
#define OFF_OPSB    (OFF_WRT + 16384)        // bf16 [32][128(o)][128(d)] ternary q
#define OFF_WMIXA   (OFF_OPSB + 1048576)     // bf16 [128(r)][128(o)]
#define OFF_WWVB    (OFF_WMIXA + 32768)      // bf16 [128(o2)][128(d)]
#define OFF_MRS     (OFF_WWVB + 32768)       // f32  [128(d)][16(j)]
#define OFF_MWS     (OFF_MRS + 8192)         // f32  [128(d)][16(j)]
#define OFF_SB      (OFF_MWS + 8192)         // f32  [16(j)][128(r)]
#define OFF_SLOTS   (OFF_SB + 8192)          // f32  [16][128]
#define OFF_WWG     (OFF_SLOTS + 8192)       // f32  [128]
#define OFF_GAMMA   (OFF_WWG + 512)
#define OFF_BETA    (OFF_GAMMA + 512)
#define OFF_WSC     (OFF_BETA + 512)
#define OFF_RF      (OFF_WSC + 256)          // bf16 [16384][128]
#define WS_TOTAL    (OFF_RF + 4194304)

// ---------------- d_out scratch regions (bytes) ----------------------------
#define D_X    0                             // f32 [16384][128] reason
#define D_Y0   (8u << 20)                    // f32 [16384][128]
#define D_XB   (16u << 20)                   // bf16 [16384][128]
#define D_AO   (20u << 20)                   // bf16 [16384][128]
#define D_COEF (24u << 20)                   // f32 [16384][32]
#define D_GP   (26u << 20)                   // f32 [16384]

// --------------------------- scale reductions ------------------------------
__global__ __launch_bounds__(256) void k_absum(const float* __restrict__ w, int n,
                                               float* __restrict__ out) {
  __shared__ float ws4[4];
  float s = 0.f;
  for (int i = blockIdx.x * 256 + threadIdx.x; i < n; i += gridDim.x * 256)
    s += fabsf(w[i]);
  s = waveRed(s);
  int lane = threadIdx.x & 63, wv = threadIdx.x >> 6;
  if (lane == 0) ws4[wv] = s;
  __syncthreads();
  if (threadIdx.x == 0) atomicAdd(out, ws4[0] + ws4[1] + ws4[2] + ws4[3]);
}

__global__ __launch_bounds__(256) void k_absum_ops(const float* __restrict__ ops,
                                                   float* __restrict__ outs) {
  __shared__ float ws4[4];
  const int n = blockIdx.y;
  const float* w = ops + (size_t)n * (DR * DR);
  float s = 0.f;
  for (int i = blockIdx.x * 256 + threadIdx.x; i < DR * DR; i += gridDim.x * 256)
    s += fabsf(w[i]);
  s = waveRed(s);
  int lane = threadIdx.x & 63, wv = threadIdx.x >> 6;
  if (lane == 0) ws4[wv] = s;
  __syncthreads();
  if (threadIdx.x == 0) atomicAdd(&outs[n], ws4[0] + ws4[1] + ws4[2] + ws4[3]);
}

// --------------------------- weight build ----------------------------------
__global__ __launch_bounds__(256) void k_build(
    const float* __restrict__ W_down, const float* __restrict__ W_up,
    const float* __restrict__ W_router, const float* __restrict__ ops,
    const float* __restrict__ W_read, const float* __restrict__ W_wk,
    const float* __restrict__ W_wg, const float* __restrict__ W_wv,
    const float* __restrict__ W_mix, const float* __restrict__ slots,
    const float* __restrict__ gamma, const float* __restrict__ beta,
    const float* __restrict__ wscale, int has_wsc, const float* __restrict__ sums,
    ushort* __restrict__ WdE, ushort* __restrict__ WuE, float* __restrict__ WrT,
    ushort* __restrict__ opsB, float* __restrict__ opsScale,
    ushort* __restrict__ WmixA, ushort* __restrict__ WwvB,
    float* __restrict__ Mrs, float* __restrict__ Mws, float* __restrict__ SBw,
    float* __restrict__ slotsF, float* __restrict__ WwgF,
    float* __restrict__ gammaF, float* __restrict__ betaF, float* __restrict__ wscF) {
  int id = blockIdx.x * 256 + threadIdx.x;
  const float s_wd = fmaxf(sums[0] * (1.f / 131072.f), 1e-5f);
  const float s_wr = fmaxf(sums[1] * (1.f / 4096.f), 1e-5f);
  const float s_wu = fmaxf(sums[2] * (1.f / 131072.f), 1e-5f);

  if (id < 131072) { WdE[id] = f2b_bits(qeff(W_down[id], s_wd)); return; }
  id -= 131072;
  if (id < 131072) { WuE[id] = f2b_bits(qeff(W_up[id], s_wu)); return; }
  id -= 131072;
  if (id < 4096) {              // WrT[d][n] = qeff(W_router[n][d])
    int d = id >> 5, n = id & 31;
    WrT[id] = qeff(W_router[n * DR + d], s_wr);
    return;
  }
  id -= 4096;
  if (id < 524288) {            // opsB[n][o][d] = ternary q (bf16 exact)
    int n = id >> 14;
    float s = fmaxf(sums[3 + n] * (1.f / 16384.f), 1e-5f);
    float q = rintf(ops[id] / s);
    q = fminf(1.f, fmaxf(-1.f, q));
    opsB[id] = f2b_bits(q);
    return;
  }
  id -= 524288;
  if (id < 32) { opsScale[id] = fmaxf(sums[3 + id] * (1.f / 16384.f), 1e-5f); return; }
  id -= 32;
  if (id < 16384) {             // WmixA[r][o] = W_mix[r][o]
    int r = id >> 7, o = id & 127;
    WmixA[id] = f2b_bits(W_mix[r * 256 + o]);
    return;
  }
  id -= 16384;
  if (id < 16384) { WwvB[id] = f2b_bits(W_wv[id]); return; }   // [o2][d] as-is
  id -= 16384;
  if (id < 2048) {              // Mrs[d][j] = sum_o W_read[o][d]*slots[j][o]
    int d = id >> 4, j = id & 15;
    float a = 0.f;
    for (int o = 0; o < DR; ++o) a += W_read[o * DR + d] * slots[j * DR + o];
    Mrs[id] = a;
    return;
  }
  id -= 2048;
  if (id < 2048) {              // Mws[d][j] = sum_o W_wk[o][d]*slots[j][o]
    int d = id >> 4, j = id & 15;
    float a = 0.f;
    for (int o = 0; o < DR; ++o) a += W_wk[o * DR + d] * slots[j * DR + o];
    Mws[id] = a;
    return;
  }
  id -= 2048;
  if (id < 2048) {              // SB[j][r] = sum_o slots[j][o]*W_mix[r][128+o]
    int j = id >> 7, r = id & 127;
    float a = 0.f;
    for (int o = 0; o < DR; ++o) a += slots[j * DR + o] * W_mix[r * 256 + 128 + o];
    SBw[id] = a;
    return;
  }
  id -= 2048;
  if (id < 2048) { slotsF[id] = slots[id]; return; }
  id -= 2048;
  if (id < 128) { WwgF[id] = W_wg[id]; return; }
  id -= 128;
  if (id < 128) { gammaF[id] = gamma[id]; return; }
  id -= 128;
  if (id < 128) { betaF[id] = beta[id]; return; }
  id -= 128;
  if (id == 0) { wscF[0] = has_wsc ? wscale[0] : 0.01f; }
}

// ------------------- down projection: MFMA bf16 GEMM -----------------------
__global__ __launch_bounds__(256) void k_down(const float* __restrict__ hidden,
                                              const ushort* __restrict__ WdE,
                                              float* __restrict__ X) {
  const int wave = threadIdx.x >> 6, lane = threadIdx.x & 63;
  const int quad = lane >> 4, mrow = lane & 15;
  const int m0 = blockIdx.x * 64 + wave * 16;

  f32x4 acc[8];
#pragma unroll
  for (int i = 0; i < 8; ++i) acc[i] = (f32x4){0.f, 0.f, 0.f, 0.f};

  const float* Ap = hidden + (size_t)(m0 + mrow) * DM + quad * 8;
  for (int kt = 0; kt < 32; ++kt) {
    float4 a0 = *(const float4*)(Ap + kt * 32);
    float4 a1 = *(const float4*)(Ap + kt * 32 + 4);
    bfrag a;
    a[0] = (short)f2b_bits(a0.x); a[1] = (short)f2b_bits(a0.y);
    a[2] = (short)f2b_bits(a0.z); a[3] = (short)f2b_bits(a0.w);
    a[4] = (short)f2b_bits(a1.x); a[5] = (short)f2b_bits(a1.y);
    a[6] = (short)f2b_bits(a1.z); a[7] = (short)f2b_bits(a1.w);
#pragma unroll
    for (int nt = 0; nt < 8; ++nt) {
      const ushort* Bp = WdE + (size_t)(nt * 16 + mrow) * DM + kt * 32 + quad * 8;
      bfrag b = *(const bfrag*)Bp;
      acc[nt] = __builtin_amdgcn_mfma_f32_16x16x32_bf16(a, b, acc[nt], 0, 0, 0);
    }
  }
#pragma unroll
  for (int nt = 0; nt < 8; ++nt)
#pragma unroll
    for (int r = 0; r < 4; ++r)
      X[(size_t)(m0 + quad * 4 + r) * DR + nt * 16 + mrow] = acc[nt][r];
}

// ----------------- router / scores / coef / Y0 (per pass) ------------------
__global__ __launch_bounds__(256) void k_router(
    const float* __restrict__ X, ushort* __restrict__ XB,
    float* __restrict__ COEFo, float* __restrict__ Y0,
    const float* __restrict__ WrT, const float* __restrict__ opsScale,
    const float* __restrict__ Mrs, const float* __restrict__ SBw) {
  __shared__ float xs[64][128];
  __shared__ float lg[64][32];
  __shared__ float at[64][16];
  __shared__ int   seli[64][2];
  __shared__ float selw[64][2];

  const int tid = threadIdx.x;
  const int t0 = blockIdx.x * 64;

  for (int i = tid; i < 8192; i += 256) {
    float v = X[(size_t)t0 * DR + i];
    xs[i >> 7][i & 127] = v;
    XB[(size_t)t0 * DR + i] = f2b_bits(v);
  }
  __syncthreads();

  // router logits
  for (int p = tid; p < 2048; p += 256) {
    int t = p >> 5, n = p & 31;
    float a = 0.f;
    for (int d = 0; d < DR; ++d) a += xs[t][d] * WrT[d * 32 + n];
    lg[t][n] = a;
  }
  // slot attention scores via rank-16 precompute
  for (int p = tid; p < 1024; p += 256) {
    int t = p >> 4, j = p & 15;
    float a = 0.f;
    for (int d = 0; d < DR; ++d) a += xs[t][d] * Mrs[d * 16 + j];
    at[t][j] = a * 0.088388347648318447f;
  }
  __syncthreads();

  if (tid < 64) {
    // exact top-2 (first-occurrence), softmax of 2
    float v0 = -1e30f; int i0 = 0;
#pragma unroll
    for (int n = 0; n < 32; ++n) { float v = lg[tid][n]; if (v > v0) { v0 = v; i0 = n; } }
    float v1 = -1e30f; int i1 = 0;
#pragma unroll
    for (int n = 0; n < 32; ++n)
      if (n != i0) { float v = lg[tid][n]; if (v > v1) { v1 = v; i1 = n; } }
    float e = expf(v1 - v0);
    float w0 = 1.f / (1.f + e);
    seli[tid][0] = i0; seli[tid][1] = i1;
    selw[tid][0] = w0; selw[tid][1] = e * w0;
    // attention softmax
    float m = -1e30f;
#pragma unroll
    for (int j = 0; j < 16; ++j) m = fmaxf(m, at[tid][j]);
    float s = 0.f;
#pragma unroll
    for (int j = 0; j < 16; ++j) { float ee = expf(at[tid][j] - m); at[tid][j] = ee; s += ee; }
    float inv = 1.f / s;
#pragma unroll
    for (int j = 0; j < 16; ++j) at[tid][j] *= inv;
  }
  __syncthreads();

  // coef[t][n] = (COEF + sel weight) * s_n
  for (int p = tid; p < 2048; p += 256) {
    int t = p >> 5, n = p & 31;
    float cf = COEF;
    if (n == seli[t][0]) cf += selw[t][0];
    if (n == seli[t][1]) cf += selw[t][1];
    COEFo[(size_t)(t0 + t) * 32 + n] = cf * opsScale[n];
  }
  // Y0[t][r] = attn @ SB (mem_out already pushed through W_mix_B)
  for (int p = tid; p < 8192; p += 256) {
    int t = p >> 7, r = p & 127;
    float a = 0.f;
#pragma unroll
    for (int j = 0; j < 16; ++j) a += at[t][j] * SBw[j * 128 + r];
    Y0[(size_t)(t0 + t) * DR + r] = a;
  }
}

// ------------- op library: dense MFMA over all 32 ops ----------------------
// AO[t][o] = sum_n coef[t][n] * sum_d xb[t][d] * q_n[o][d]
__global__ __launch_bounds__(256) void k_ops(
    const ushort* __restrict__ XB, const ushort* __restrict__ opsB,
    const float* __restrict__ COEFi, ushort* __restrict__ AO) {
  const int w = threadIdx.x >> 6, lane = threadIdx.x & 63;
  const int quad = lane >> 4, mrow = lane & 15;
  const int mi = w >> 1, nh = w & 1;
  const int t0 = blockIdx.x * 32 + mi * 16;

  bfrag a[4];
  const ushort* Ap = XB + (size_t)(t0 + mrow) * DR + quad * 8;
#pragma unroll
  for (int kt = 0; kt < 4; ++kt) a[kt] = *(const bfrag*)(Ap + kt * 32);

  f32x4 out[4];
#pragma unroll
  for (int i = 0; i < 4; ++i) out[i] = (f32x4){0.f, 0.f, 0.f, 0.f};

  for (int n = 0; n < NOPS; ++n) {
    f32x4 tmp[4];
#pragma unroll
    for (int i = 0; i < 4; ++i) tmp[i] = (f32x4){0.f, 0.f, 0.f, 0.f};
    const ushort* Bb = opsB + (size_t)n * (DR * DR);
#pragma unroll
    for (int kt = 0; kt < 4; ++kt) {
#pragma unroll
      for (int nt = 0; nt < 4; ++nt) {
        const int col = (nh * 4 + nt) * 16 + mrow;
        bfrag b = *(const bfrag*)(Bb + (size_t)col * DR + kt * 32 + quad * 8);
        tmp[nt] = __builtin_amdgcn_mfma_f32_16x16x32_bf16(a[kt], b, tmp[nt], 0, 0, 0);
      }
    }
    float cf[4];
#pragma unroll
    for (int r = 0; r < 4; ++r) cf[r] = COEFi[(size_t)(t0 + quad * 4 + r) * 32 + n];
#pragma unroll
    for (int nt = 0; nt < 4; ++nt)
#pragma unroll
      for (int r = 0; r < 4; ++r) out[nt][r] += cf[r] * tmp[nt][r];
  }
#pragma unroll
  for (int nt = 0; nt < 4; ++nt)
#pragma unroll
    for (int r = 0; r < 4; ++r) {
      const int tok = t0 + quad * 4 + r;
      const int col = (nh * 4 + nt) * 16 + mrow;
      AO[(size_t)tok * DR + col] = f2b_bits(out[nt][r]);
    }
}

// ----------- mix GEMM + residual + LayerNorm (in-place on X) ---------------
// X[t][r] = LN( X + AO@WmixA^T + Y0 )
__global__ __launch_bounds__(256) void k_mix_ln(
    const ushort* __restrict__ AO, const ushort* __restrict__ WmixA,
    float* __restrict__ X, const float* __restrict__ Y0,
    const float* __restrict__ gammaF, const float* __restrict__ betaF) {
  const int w = threadIdx.x >> 6, lane = threadIdx.x & 63;
  const int quad = lane >> 4, mrow = lane & 15;
  const int t0 = blockIdx.x * 64 + w * 16;

  bfrag a[4];
  const ushort* Ap = AO + (size_t)(t0 + mrow) * DR + quad * 8;
#pragma unroll
  for (int kt = 0; kt < 4; ++kt) a[kt] = *(const bfrag*)(Ap + kt * 32);

  f32x4 acc[8];
#pragma unroll
  for (int i = 0; i < 8; ++i) acc[i] = (f32x4){0.f, 0.f, 0.f, 0.f};
#pragma unroll
  for (int kt = 0; kt < 4; ++kt)
#pragma unroll
    for (int nt = 0; nt < 8; ++nt) {
      bfrag b = *(const bfrag*)(WmixA + (size_t)(nt * 16 + mrow) * DR + kt * 32 + quad * 8);
      acc[nt] = __builtin_amdgcn_mfma_f32_16x16x32_bf16(a[kt], b, acc[nt], 0, 0, 0);
    }

  // v = x + mixed;  LN over rows via 16-lane shuffle reduce
  float v[8][4];
#pragma unroll
  for (int nt = 0; nt < 8; ++nt) {
    const int col = nt * 16 + mrow;
#pragma unroll
    for (int r = 0; r < 4; ++r) {
      const size_t idx = (size_t)(t0 + quad * 4 + r) * DR + col;
      v[nt][r] = acc[nt][r] + X[idx] + Y0[idx];
    }
  }
  float s[4], q[4];
#pragma unroll
  for (int r = 0; r < 4; ++r) {
    float ps = 0.f, pq = 0.f;
#pragma unroll
    for (int nt = 0; nt < 8; ++nt) { ps += v[nt][r]; pq += v[nt][r] * v[nt][r]; }
    s[r] = ps; q[r] = pq;
  }
#pragma unroll
  for (int m = 1; m < 16; m <<= 1)
#pragma unroll
    for (int r = 0; r < 4; ++r) {
      s[r] += __shfl_xor(s[r], m, 64);
      q[r] += __shfl_xor(q[r], m, 64);
    }
  float mu[4], rsd[4];
#pragma unroll
  for (int r = 0; r < 4; ++r) {
    mu[r] = s[r] * (1.f / DR);
    float var = q[r] * (1.f / DR) - mu[r] * mu[r];
    rsd[r] = rsqrtf(var + 1e-5f);
  }
#pragma unroll
  for (int nt = 0; nt < 8; ++nt) {
    const int col = nt * 16 + mrow;
    const float g = gammaF[col], bb = betaF[col];
#pragma unroll
    for (int r = 0; r < 4; ++r) {
      const size_t idx = (size_t)(t0 + quad * 4 + r) * DR + col;
      X[idx] = (v[nt][r] - mu[r]) * rsd[r] * g + bb;
    }
  }
}

// ---------- write-signal prep: gate + write-attention + xb -----------------
__global__ __launch_bounds__(256) void k_wprep(
    const float* __restrict__ X, ushort* __restrict__ XB,
    float* __restrict__ GP, float* __restrict__ Y0w,
    const float* __restrict__ Mws, const float* __restrict__ slotsF,
    const float* __restrict__ WwgF, const float* __restrict__ wscF) {
  __shared__ float xs[64][128];
  __shared__ float at[64][16];

  const int tid = threadIdx.x;
  const int t0 = blockIdx.x * 64;
  const float wsc = wscF[0];

  for (int i = tid; i < 8192; i += 256) {
    float v = X[(size_t)t0 * DR + i];
    xs[i >> 7][i & 127] = v;
    XB[(size_t)t0 * DR + i] = f2b_bits(v);
  }
  __syncthreads();

  for (int p = tid; p < 1024; p += 256) {
    int t = p >> 4, j = p & 15;
    float a = 0.f;
    for (int d = 0; d < DR; ++d) a += xs[t][d] * Mws[d * 16 + j];
    at[t][j] = a * 0.088388347648318447f;
  }
  __syncthreads();

  if (tid < 64) {
    float z = 0.f;
    for (int d = 0; d < DR; ++d) z += xs[tid][d] * WwgF[d];
    GP[t0 + tid] = wsc / (1.f + expf(-z));
    float m = -1e30f;
#pragma unroll
    for (int j = 0; j < 16; ++j) m = fmaxf(m, at[tid][j]);
    float sum = 0.f;
#pragma unroll
    for (int j = 0; j < 16; ++j) { float e = expf(at[tid][j] - m); at[tid][j] = e; sum += e; }
    float inv = 1.f / sum;
#pragma unroll
    for (int j = 0; j < 16; ++j) at[tid][j] *= inv;
  }
  __syncthreads();

  const float c = wsc * 0.1f;
  for (int p = tid; p < 8192; p += 256) {
    int t = p >> 7, r = p & 127;
    float a = 0.f;
#pragma unroll
    for (int j = 0; j < 16; ++j) a += at[t][j] * slotsF[j * DR + r];
    Y0w[(size_t)(t0 + t) * DR + r] = c * a;
  }
}

// ---------- wv GEMM + write-signal combine -> RF (bf16) --------------------
// RF[t][o2] = X + GP[t]*(xb@Wwv^T) + Y0w
__global__ __launch_bounds__(256) void k_wv(
    const ushort* __restrict__ XB, const ushort* __restrict__ WwvB,
    const float* __restrict__ X, const float* __restrict__ GP,
    const float* __restrict__ Y0w, ushort* __restrict__ RF) {
  const int w = threadIdx.x >> 6, lane = threadIdx.x & 63;
  const int quad = lane >> 4, mrow = lane & 15;
  const int t0 = blockIdx.x * 64 + w * 16;

  bfrag a[4];
  const ushort* Ap = XB + (size_t)(t0 + mrow) * DR + quad * 8;
#pragma unroll
  for (int kt = 0; kt < 4; ++kt) a[kt] = *(const bfrag*)(Ap + kt * 32);

  f32x4 acc[8];
#pragma unroll
  for (int i = 0; i < 8; ++i) acc[i] = (f32x4){0.f, 0.f, 0.f, 0.f};
#pragma unroll
  for (int kt = 0; kt < 4; ++kt)
#pragma unroll
    for (int nt = 0; nt < 8; ++nt) {
      bfrag b = *(const bfrag*)(WwvB + (size_t)(nt * 16 + mrow) * DR + kt * 32 + quad * 8);
      acc[nt] = __builtin_amdgcn_mfma_f32_16x16x32_bf16(a[kt], b, acc[nt], 0, 0, 0);
    }

  float gp[4];
#pragma unroll
  for (int r = 0; r < 4; ++r) gp[r] = GP[t0 + quad * 4 + r];
#pragma unroll
  for (int nt = 0; nt < 8; ++nt) {
    const int col = nt * 16 + mrow;
#pragma unroll
    for (int r = 0; r < 4; ++r) {
      const size_t idx = (size_t)(t0 + quad * 4 + r) * DR + col;
      RF[idx] = f2b_bits(X[idx] + gp[r] * acc[nt][r] + Y0w[idx]);
    }
  }
}

// -------------------- up projection + residual (MFMA) ----------------------
__global__ __launch_bounds__(256) void k_up(const ushort* __restrict__ Rf,
                                            const ushort* __restrict__ WuE,
                                            const float* __restrict__ hidden,
                                            float* __restrict__ out) {
  const int wave = threadIdx.x >> 6, lane = threadIdx.x & 63;
  const int quad = lane >> 4, mrow = lane & 15;
  const int mt = blockIdx.x >> 3, ngrp = blockIdx.x & 7;
  const int m0 = mt * 64 + wave * 16;
  const int ng = ngrp * 8;

  f32x4 acc[8];
#pragma unroll
  for (int i = 0; i < 8; ++i) acc[i] = (f32x4){0.f, 0.f, 0.f, 0.f};

  const ushort* Ap = Rf + (size_t)(m0 + mrow) * DR + quad * 8;
#pragma unroll
  for (int kt = 0; kt < 4; ++kt) {
    bfrag a = *(const bfrag*)(Ap + kt * 32);
#pragma unroll
    for (int nt = 0; nt < 8; ++nt) {
      const ushort* Bp = WuE + (size_t)((ng + nt) * 16 + mrow) * DR + kt * 32 + quad * 8;
      bfrag b = *(const bfrag*)Bp;
      acc[nt] = __builtin_amdgcn_mfma_f32_16x16x32_bf16(a, b, acc[nt], 0, 0, 0);
    }
  }
#pragma unroll
  for (int nt = 0; nt < 8; ++nt)
#pragma unroll
    for (int r = 0; r < 4; ++r) {
      const int token = m0 + quad * 4 + r;
      const int j = (ng + nt) * 16 + mrow;
      const size_t idx = (size_t)token * DM + j;
      out[idx] = hidden[idx] + acc[nt][r];
    }
}

// ---------------------------------------------------------------------------
extern "C" void kernel_launch(void* const* d_in, const int* in_sizes, int n_in,
                              void* d_out, int out_size, void* d_ws, size_t ws_size,
                              hipStream_t stream) {
  int ns[20]; int nn = 0; int lastsc = -1;
  for (int i = 0; i < n_in; ++i) {
    if (in_sizes[i] == 1) lastsc = i;
    else if (nn < 20) ns[nn++] = i;
  }
  int iH = 0, iWd = 2, iWu = 3, iOps = 4, iWr = 5, iSl = 6, iRe = 7,
      iWk = 8, iWg = 9, iWv = 10, iMx = 11, iG = 12, iB = 13;
  if (nn >= 13) {
    iH  = ns[0];  iWd = ns[1];  iWu = ns[2];  iOps = ns[3]; iWr = ns[4];
    iSl = ns[5];  iRe = ns[6];  iWk = ns[7];  iWg = ns[8];  iWv = ns[9];
    iMx = ns[10]; iG  = ns[11]; iB  = ns[12];
  }
  const float* hidden   = (const float*)d_in[iH];
  const float* W_down   = (const float*)d_in[iWd];
  const float* W_up     = (const float*)d_in[iWu];
  const float* opsw     = (const float*)d_in[iOps];
  const float* W_router = (const float*)d_in[iWr];
  const float* slots    = (const float*)d_in[iSl];
  const float* W_read   = (const float*)d_in[iRe];
  const float* W_wk     = (const float*)d_in[iWk];
  const float* W_wg     = (const float*)d_in[iWg];
  const float* W_wv     = (const float*)d_in[iWv];
  const float* W_mix    = (const float*)d_in[iMx];
  const float* lng      = (const float*)d_in[iG];
  const float* lnb      = (const float*)d_in[iB];
  const float* wscale   = (lastsc >= 0) ? (const float*)d_in[lastsc] : (const float*)d_in[iG];
  const int has_wsc     = (lastsc >= 0) ? 1 : 0;

  char* ws = (char*)d_ws;
  float*  sums   = (float*)(ws + OFF_SUMS);
  float*  opsSc  = (float*)(ws + OFF_OPSSC);
  ushort* WdE    = (ushort*)(ws + OFF_WDE);
  ushort* WuE    = (ushort*)(ws + OFF_WUE);
  float*  WrT    = (float*)(ws + OFF_WRT);
  ushort* opsB   = (ushort*)(ws + OFF_OPSB);
  ushort* WmixA  = (ushort*)(ws + OFF_WMIXA);
  ushort* WwvB   = (ushort*)(ws + OFF_WWVB);
  float*  Mrs    = (float*)(ws + OFF_MRS);
  float*  Mws    = (float*)(ws + OFF_MWS);
  float*  SBw    = (float*)(ws + OFF_SB);
  float*  slotsF = (float*)(ws + OFF_SLOTS);
  float*  WwgF   = (float*)(ws + OFF_WWG);
  float*  gammaF = (float*)(ws + OFF_GAMMA);
  float*  betaF  = (float*)(ws + OFF_BETA);
  float*  wscF   = (float*)(ws + OFF_WSC);
  ushort* RF     = (ushort*)(ws + OFF_RF);

  char* od = (char*)d_out;
  float*  X    = (float*)(od + D_X);
  float*  Y0   = (float*)(od + D_Y0);
  ushort* XB   = (ushort*)(od + D_XB);
  ushort* AO   = (ushort*)(od + D_AO);
  float*  CO   = (float*)(od + D_COEF);
  float*  GP   = (float*)(od + D_GP);

  hipMemsetAsync(ws + OFF_SUMS, 0, 256, stream);
  k_absum<<<128, 256, 0, stream>>>(W_down, 131072, &sums[0]);
  k_absum<<<4, 256, 0, stream>>>(W_router, 4096, &sums[1]);
  k_absum<<<128, 256, 0, stream>>>(W_up, 131072, &sums[2]);
  k_absum_ops<<<dim3(4, 32), 256, 0, stream>>>(opsw, sums + 3);
  k_build<<<3250, 256, 0, stream>>>(W_down, W_up, W_router, opsw, W_read, W_wk, W_wg,
                                    W_wv, W_mix, slots, lng, lnb, wscale, has_wsc,
                                    sums, WdE, WuE, WrT, opsB, opsSc, WmixA, WwvB,
                                    Mrs, Mws, SBw, slotsF, WwgF, gammaF, betaF, wscF);
  k_down<<<256, 256, 0, stream>>>(hidden, WdE, X);
  for (int pass = 0; pass < 2; ++pass) {
    k_router<<<256, 256, 0, stream>>>(X, XB, CO, Y0, WrT, opsSc, Mrs, SBw);
    k_ops<<<512, 256, 0, stream>>>(XB, opsB, CO, AO);
    k_mix_ln<<<256, 256, 0, stream>>>(AO, WmixA, X, Y0, gammaF, betaF);
  }
  k_wprep<<<256, 256, 0, stream>>>(X, XB, GP, Y0, Mws, slotsF, WwgF, wscF);
  k_wv<<<256, 256, 0, stream>>>(XB, WwvB, X, GP, Y0, RF);
  k_up<<<2048, 256, 0, stream>>>(RF, WuE, hidden, X);
}

// Round 6
// 397.589 us; speedup vs baseline: 1.7679x; 1.6073x over previous
//
#include <hip/hip_runtime.h>

// ---------------------------------------------------------------------------
// RCSM engine, MI355X/gfx950.  FP32 in/out.  Round 6: fused pass kernel.
//  * one kernel per pass: router+top2+attn (VALU) -> 32-op MFMA GEMM with
//    register-prefetched B and per-CU-unique L2 fragment reads ->
//    mix GEMM + residual + rank-16 mem term + LayerNorm.  No intermediate
//    global traffic.
//  * k_wsig: fused write-signal (gate + write-attn + wv GEMM + combine).
//  * k_down: 512 blocks (8 waves/CU) for latency hiding.
// ---------------------------------------------------------------------------

#define DR   128
#define DM   1024
#define NTOK 16384
#define NOPS 32
#define COEF (1e-5f / 32.f)

typedef __attribute__((ext_vector_type(8))) short bfrag;   // 8 x bf16 bits
typedef __attribute__((ext_vector_type(4))) float f32x4;

__device__ __forceinline__ ushort f2b_bits(float f) {
  union { float f; uint i; } c; c.f = f;
  uint x = c.i;
  return (ushort)((x + 0x7fffu + ((x >> 16) & 1u)) >> 16);   // RNE
}
__device__ __forceinline__ float qeff(float w, float s) {
  float q = rintf(w / s);
  q = fminf(1.f, fmaxf(-1.f, q));
  return q * s;
}
__device__ __forceinline__ float waveRed(float v) {
#pragma unroll
  for (int m = 32; m > 0; m >>= 1) v += __shfl_xor(v, m, 64);
  return v;
}

// ---------------- ws layout (bytes; total ~5.9 MB) -------------------------
#define OFF_SUMS    0                        // 64 f32
#define OFF_OPSSC   256                      // 32 f32
#define OFF_WDE     512                      // bf16 [128][1024]
#define OFF_WUE     (OFF_WDE + 262144)       // bf16 [1024][128]
#define OFF_WRT     (OFF_WUE + 262144)       // f32  [128(d)][32(n)]
#define OFF_OPSB    (OFF_WRT + 16384)        // bf16 [32][128(o)][128(d)] ternary q
#define OFF_WMIXA   (OFF_OPSB + 1048576)     // bf16 [128(r)][128(o)]
#define OFF_WWVB    (OFF_WMIXA + 32768)      // bf16 [128(o2)][128(d)]
#define OFF_MRS     (OFF_WWVB + 32768)       // f32  [128(d)][16(j)]
#define OFF_MWS     (OFF_MRS + 8192)         // f32  [128(d)][16(j)]
#define OFF_SB      (OFF_MWS + 8192)         // f32  [16(j)][128(r)]
#define OFF_SLOTS   (OFF_SB + 8192)          // f32  [16][128]
#define OFF_WWG     (OFF_SLOTS + 8192)       // f32  [128]
#define OFF_GAMMA   (OFF_WWG + 512)
#define OFF_BETA    (OFF_GAMMA + 512)
#define OFF_WSC     (OFF_BETA + 512)
#define OFF_RF      (OFF_WSC + 256)          // bf16 [16384][128]
#define WS_TOTAL    (OFF_RF + 4194304)

// --------------------------- scale reductions ------------------------------
__global__ __launch_bounds__(256) void k_absum(const float* __restrict__ w, int n,
                                               float* __restrict__ out) {
  __shared__ float ws4[4];
  float s = 0.f;
  for (int i = blockIdx.x * 256 + threadIdx.x; i < n; i += gridDim.x * 256)
    s += fabsf(w[i]);
  s = waveRed(s);
  int lane = threadIdx.x & 63, wv = threadIdx.x >> 6;
  if (lane == 0) ws4[wv] = s;
  __syncthreads();
  if (threadIdx.x == 0) atomicAdd(out, ws4[0] + ws4[1] + ws4[2] + ws4[3]);
}

__global__ __launch_bounds__(256) void k_absum_ops(const float* __restrict__ ops,
                                                   float* __restrict__ outs) {
  __shared__ float ws4[4];
  const int n = blockIdx.y;
  const float* w = ops + (size_t)n * (DR * DR);
  float s = 0.f;
  for (int i = blockIdx.x * 256 + threadIdx.x; i < DR * DR; i += gridDim.x * 256)
    s += fabsf(w[i]);
  s = waveRed(s);
  int lane = threadIdx.x & 63, wv = threadIdx.x >> 6;
  if (lane == 0) ws4[wv] = s;
  __syncthreads();
  if (threadIdx.x == 0) atomicAdd(&outs[n], ws4[0] + ws4[1] + ws4[2] + ws4[3]);
}

// --------------------------- weight build ----------------------------------
__global__ __launch_bounds__(256) void k_build(
    const float* __restrict__ W_down, const float* __restrict__ W_up,
    const float* __restrict__ W_router, const float* __restrict__ ops,
    const float* __restrict__ W_read, const float* __restrict__ W_wk,
    const float* __restrict__ W_wg, const float* __restrict__ W_wv,
    const float* __restrict__ W_mix, const float* __restrict__ slots,
    const float* __restrict__ gamma, const float* __restrict__ beta,
    const float* __restrict__ wscale, int has_wsc, const float* __restrict__ sums,
    ushort* __restrict__ WdE, ushort* __restrict__ WuE, float* __restrict__ WrT,
    ushort* __restrict__ opsB, float* __restrict__ opsScale,
    ushort* __restrict__ WmixA, ushort* __restrict__ WwvB,
    float* __restrict__ Mrs, float* __restrict__ Mws, float* __restrict__ SBw,
    float* __restrict__ slotsF, float* __restrict__ WwgF,
    float* __restrict__ gammaF, float* __restrict__ betaF, float* __restrict__ wscF) {
  int id = blockIdx.x * 256 + threadIdx.x;
  const float s_wd = fmaxf(sums[0] * (1.f / 131072.f), 1e-5f);
  const float s_wr = fmaxf(sums[1] * (1.f / 4096.f), 1e-5f);
  const float s_wu = fmaxf(sums[2] * (1.f / 131072.f), 1e-5f);

  if (id < 131072) { WdE[id] = f2b_bits(qeff(W_down[id], s_wd)); return; }
  id -= 131072;
  if (id < 131072) { WuE[id] = f2b_bits(qeff(W_up[id], s_wu)); return; }
  id -= 131072;
  if (id < 4096) {
    int d = id >> 5, n = id & 31;
    WrT[id] = qeff(W_router[n * DR + d], s_wr);
    return;
  }
  id -= 4096;
  if (id < 524288) {            // opsB[n][o][d] = ternary q (bf16 exact)
    int n = id >> 14;
    float s = fmaxf(sums[3 + n] * (1.f / 16384.f), 1e-5f);
    float q = rintf(ops[id] / s);
    q = fminf(1.f, fmaxf(-1.f, q));
    opsB[id] = f2b_bits(q);
    return;
  }
  id -= 524288;
  if (id < 32) { opsScale[id] = fmaxf(sums[3 + id] * (1.f / 16384.f), 1e-5f); return; }
  id -= 32;
  if (id < 16384) {             // WmixA[r][o]
    int r = id >> 7, o = id & 127;
    WmixA[id] = f2b_bits(W_mix[r * 256 + o]);
    return;
  }
  id -= 16384;
  if (id < 16384) { WwvB[id] = f2b_bits(W_wv[id]); return; }
  id -= 16384;
  if (id < 2048) {              // Mrs[d][j]
    int d = id >> 4, j = id & 15;
    float a = 0.f;
    for (int o = 0; o < DR; ++o) a += W_read[o * DR + d] * slots[j * DR + o];
    Mrs[id] = a;
    return;
  }
  id -= 2048;
  if (id < 2048) {              // Mws[d][j]
    int d = id >> 4, j = id & 15;
    float a = 0.f;
    for (int o = 0; o < DR; ++o) a += W_wk[o * DR + d] * slots[j * DR + o];
    Mws[id] = a;
    return;
  }
  id -= 2048;
  if (id < 2048) {              // SB[j][r]
    int j = id >> 7, r = id & 127;
    float a = 0.f;
    for (int o = 0; o < DR; ++o) a += slots[j * DR + o] * W_mix[r * 256 + 128 + o];
    SBw[id] = a;
    return;
  }
  id -= 2048;
  if (id < 2048) { slotsF[id] = slots[id]; return; }
  id -= 2048;
  if (id < 128) { WwgF[id] = W_wg[id]; return; }
  id -= 128;
  if (id < 128) { gammaF[id] = gamma[id]; return; }
  id -= 128;
  if (id < 128) { betaF[id] = beta[id]; return; }
  id -= 128;
  if (id == 0) { wscF[0] = has_wsc ? wscale[0] : 0.01f; }
}

// ------------------- down projection: MFMA bf16 GEMM -----------------------
// 512 blocks, 32 tokens/block; wave (w&1)=token half, (w>>1)=col half.
__global__ __launch_bounds__(256) void k_down(const float* __restrict__ hidden,
                                              const ushort* __restrict__ WdE,
                                              float* __restrict__ X) {
  const int w = threadIdx.x >> 6, lane = threadIdx.x & 63;
  const int quad = lane >> 4, mrow = lane & 15;
  const int m0 = blockIdx.x * 32 + (w & 1) * 16;
  const int c0 = (w >> 1) * 64;

  f32x4 acc[4];
#pragma unroll
  for (int i = 0; i < 4; ++i) acc[i] = (f32x4){0.f, 0.f, 0.f, 0.f};

  const float* Ap = hidden + (size_t)(m0 + mrow) * DM + quad * 8;
  for (int kt = 0; kt < 32; ++kt) {
    float4 a0 = *(const float4*)(Ap + kt * 32);
    float4 a1 = *(const float4*)(Ap + kt * 32 + 4);
    bfrag a;
    a[0] = (short)f2b_bits(a0.x); a[1] = (short)f2b_bits(a0.y);
    a[2] = (short)f2b_bits(a0.z); a[3] = (short)f2b_bits(a0.w);
    a[4] = (short)f2b_bits(a1.x); a[5] = (short)f2b_bits(a1.y);
    a[6] = (short)f2b_bits(a1.z); a[7] = (short)f2b_bits(a1.w);
#pragma unroll
    for (int nt = 0; nt < 4; ++nt) {
      bfrag b = *(const bfrag*)(WdE + (size_t)(c0 + nt * 16 + mrow) * DM + kt * 32 + quad * 8);
      acc[nt] = __builtin_amdgcn_mfma_f32_16x16x32_bf16(a, b, acc[nt], 0, 0, 0);
    }
  }
#pragma unroll
  for (int nt = 0; nt < 4; ++nt)
#pragma unroll
    for (int r = 0; r < 4; ++r)
      X[(size_t)(m0 + quad * 4 + r) * DR + c0 + nt * 16 + mrow] = acc[nt][r];
}

// -------------------------- fused pass kernel ------------------------------
// 256 blocks x 512 threads; 64 tokens/block; X updated in-place.
__global__ __launch_bounds__(512) void k_pass2(
    float* __restrict__ X,
    const float* __restrict__ WrT, const ushort* __restrict__ opsB,
    const float* __restrict__ opsScale, const ushort* __restrict__ WmixA,
    const float* __restrict__ Mrs, const float* __restrict__ SBw,
    const float* __restrict__ gammaF, const float* __restrict__ betaF) {
  __shared__ float  xsf[64][128];      // 32 KB
  __shared__ ushort xsb[64][136];      // 17 KB (padded: bank-conflict-free)
  __shared__ float  lg[64][32];        // 8 KB
  __shared__ float  coefT[32][64];     // 8 KB  [n][t]
  __shared__ float  attn[64][16];      // 4 KB
  __shared__ int    seli[64][2];
  __shared__ float  selw[64][2];

  const int tid = threadIdx.x;
  const int w = tid >> 6, lane = tid & 63;
  const int quad = lane >> 4, mrow = lane & 15;
  const int t0 = blockIdx.x * 64;

  // ---- P0: load X tile -> fp32 + bf16 LDS copies
  for (int i = tid; i < 2048; i += 512) {
    float4 v = *(const float4*)(X + (size_t)t0 * DR + i * 4);
    int t = i >> 5, c = (i & 31) * 4;
    xsf[t][c] = v.x; xsf[t][c + 1] = v.y; xsf[t][c + 2] = v.z; xsf[t][c + 3] = v.w;
    xsb[t][c] = f2b_bits(v.x); xsb[t][c + 1] = f2b_bits(v.y);
    xsb[t][c + 2] = f2b_bits(v.z); xsb[t][c + 3] = f2b_bits(v.w);
  }
  __syncthreads();

  // ---- P1: router logits + slot scores
  for (int p = tid; p < 2048; p += 512) {
    int t = p >> 5, n = p & 31;
    float a = 0.f;
    for (int d = 0; d < DR; ++d) a += xsf[t][d] * WrT[d * 32 + n];
    lg[t][n] = a;
  }
  for (int p = tid; p < 1024; p += 512) {
    int t = p >> 4, j = p & 15;
    float a = 0.f;
    for (int d = 0; d < DR; ++d) a += xsf[t][d] * Mrs[d * 16 + j];
    attn[t][j] = a * 0.088388347648318447f;
  }
  __syncthreads();

  if (tid < 64) {
    float v0 = -1e30f; int i0 = 0;
#pragma unroll
    for (int n = 0; n < 32; ++n) { float v = lg[tid][n]; if (v > v0) { v0 = v; i0 = n; } }
    float v1 = -1e30f; int i1 = 0;
#pragma unroll
    for (int n = 0; n < 32; ++n)
      if (n != i0) { float v = lg[tid][n]; if (v > v1) { v1 = v; i1 = n; } }
    float e = expf(v1 - v0);
    float w0 = 1.f / (1.f + e);
    seli[tid][0] = i0; seli[tid][1] = i1;
    selw[tid][0] = w0; selw[tid][1] = e * w0;
    float m = -1e30f;
#pragma unroll
    for (int j = 0; j < 16; ++j) m = fmaxf(m, attn[tid][j]);
    float s = 0.f;
#pragma unroll
    for (int j = 0; j < 16; ++j) { float ee = expf(attn[tid][j] - m); attn[tid][j] = ee; s += ee; }
    float inv = 1.f / s;
#pragma unroll
    for (int j = 0; j < 16; ++j) attn[tid][j] *= inv;
  }
  __syncthreads();

  for (int p = tid; p < 2048; p += 512) {
    int n = p >> 6, t = p & 63;
    float cf = COEF;
    if (n == seli[t][0]) cf += selw[t][0];
    if (n == seli[t][1]) cf += selw[t][1];
    coefT[n][t] = cf * opsScale[n];
  }
  __syncthreads();

  // ---- P2: 32-op MFMA GEMM.  Wave w owns cols w*16..w*16+15, all 64 tokens.
  bfrag a[4][4];
#pragma unroll
  for (int m = 0; m < 4; ++m)
#pragma unroll
    for (int kt = 0; kt < 4; ++kt)
      a[m][kt] = *(const bfrag*)&xsb[m * 16 + mrow][kt * 32 + quad * 8];

  const ushort* Bp = opsB + (size_t)(w * 16 + mrow) * DR + quad * 8;
  bfrag bc[4], bn[4];
#pragma unroll
  for (int kt = 0; kt < 4; ++kt) bc[kt] = *(const bfrag*)(Bp + kt * 32);

  f32x4 out[4];
#pragma unroll
  for (int m = 0; m < 4; ++m) out[m] = (f32x4){0.f, 0.f, 0.f, 0.f};

  for (int n = 0; n < NOPS; ++n) {
    if (n + 1 < NOPS) {
      const ushort* Bn = Bp + (size_t)(n + 1) * (DR * DR);
#pragma unroll
      for (int kt = 0; kt < 4; ++kt) bn[kt] = *(const bfrag*)(Bn + kt * 32);
    }
    f32x4 tmp[4];
#pragma unroll
    for (int m = 0; m < 4; ++m) tmp[m] = (f32x4){0.f, 0.f, 0.f, 0.f};
#pragma unroll
    for (int kt = 0; kt < 4; ++kt)
#pragma unroll
      for (int m = 0; m < 4; ++m)
        tmp[m] = __builtin_amdgcn_mfma_f32_16x16x32_bf16(a[m][kt], bc[kt], tmp[m], 0, 0, 0);
#pragma unroll
    for (int m = 0; m < 4; ++m) {
      f32x4 cf = *(const f32x4*)&coefT[n][m * 16 + quad * 4];
      out[m] += cf * tmp[m];
    }
    if (n + 1 < NOPS) {
#pragma unroll
      for (int kt = 0; kt < 4; ++kt) bc[kt] = bn[kt];
    }
  }
  __syncthreads();   // all waves done reading xsb as A

  // ---- P3: AO -> xsb (bf16, padded layout)
#pragma unroll
  for (int m = 0; m < 4; ++m)
#pragma unroll
    for (int r = 0; r < 4; ++r)
      xsb[m * 16 + quad * 4 + r][w * 16 + mrow] = f2b_bits(out[m][r]);
  __syncthreads();

  // ---- P4 (waves 0-3): mix GEMM + residual + mem term + LN -> X
  if (w < 4) {
    bfrag a2[4];
#pragma unroll
    for (int kt = 0; kt < 4; ++kt)
      a2[kt] = *(const bfrag*)&xsb[w * 16 + mrow][kt * 32 + quad * 8];

    f32x4 acc[8];
#pragma unroll
    for (int i = 0; i < 8; ++i) acc[i] = (f32x4){0.f, 0.f, 0.f, 0.f};
#pragma unroll
    for (int kt = 0; kt < 4; ++kt)
#pragma unroll
      for (int nt = 0; nt < 8; ++nt) {
        bfrag b = *(const bfrag*)(WmixA + (size_t)(nt * 16 + mrow) * DR + kt * 32 + quad * 8);
        acc[nt] = __builtin_amdgcn_mfma_f32_16x16x32_bf16(a2[kt], b, acc[nt], 0, 0, 0);
      }

    float v[8][4];
#pragma unroll
    for (int nt = 0; nt < 8; ++nt) {
      const int col = nt * 16 + mrow;
#pragma unroll
      for (int r = 0; r < 4; ++r) {
        const int t = w * 16 + quad * 4 + r;
        float y0 = 0.f;
#pragma unroll
        for (int j = 0; j < 16; ++j) y0 += attn[t][j] * SBw[j * 128 + col];
        v[nt][r] = acc[nt][r] + xsf[t][col] + y0;
      }
    }
    float s[4], q[4];
#pragma unroll
    for (int r = 0; r < 4; ++r) {
      float ps = 0.f, pq = 0.f;
#pragma unroll
      for (int nt = 0; nt < 8; ++nt) { ps += v[nt][r]; pq += v[nt][r] * v[nt][r]; }
      s[r] = ps; q[r] = pq;
    }
#pragma unroll
    for (int m = 1; m < 16; m <<= 1)
#pragma unroll
      for (int r = 0; r < 4; ++r) {
        s[r] += __shfl_xor(s[r], m, 64);
        q[r] += __shfl_xor(q[r], m, 64);
      }
    float mu[4], rsd[4];
#pragma unroll
    for (int r = 0; r < 4; ++r) {
      mu[r] = s[r] * (1.f / DR);
      float var = q[r] * (1.f / DR) - mu[r] * mu[r];
      rsd[r] = rsqrtf(var + 1e-5f);
    }
#pragma unroll
    for (int nt = 0; nt < 8; ++nt) {
      const int col = nt * 16 + mrow;
      const float g = gammaF[col], bb = betaF[col];
#pragma unroll
      for (int r = 0; r < 4; ++r) {
        const int t = w * 16 + quad * 4 + r;
        X[(size_t)(t0 + t) * DR + col] = (v[nt][r] - mu[r]) * rsd[r] * g + bb;
      }
    }
  }
}

// ------------------- fused write signal -> RF (bf16) -----------------------
__global__ __launch_bounds__(256) void k_wsig(
    const float* __restrict__ X, ushort* __restrict__ RF,
    const ushort* __restrict__ WwvB, const float* __restrict__ Mws,
    const float* __restrict__ slotsF, const float* __restrict__ WwgF,
    const float* __restrict__ wscF) {
  __shared__ float  xsf[64][128];
  __shared__ ushort xsb[64][136];
  __shared__ float  attn[64][16];
  __shared__ float  gp[64];

  const int tid = threadIdx.x;
  const int w = tid >> 6, lane = tid & 63;
  const int quad = lane >> 4, mrow = lane & 15;
  const int t0 = blockIdx.x * 64;
  const float wsc = wscF[0];

  for (int i = tid; i < 2048; i += 256) {
    float4 v = *(const float4*)(X + (size_t)t0 * DR + i * 4);
    int t = i >> 5, c = (i & 31) * 4;
    xsf[t][c] = v.x; xsf[t][c + 1] = v.y; xsf[t][c + 2] = v.z; xsf[t][c + 3] = v.w;
    xsb[t][c] = f2b_bits(v.x); xsb[t][c + 1] = f2b_bits(v.y);
    xsb[t][c + 2] = f2b_bits(v.z); xsb[t][c + 3] = f2b_bits(v.w);
  }
  __syncthreads();

  for (int p = tid; p < 1024; p += 256) {
    int t = p >> 4, j = p & 15;
    float a = 0.f;
    for (int d = 0; d < DR; ++d) a += xsf[t][d] * Mws[d * 16 + j];
    attn[t][j] = a * 0.088388347648318447f;
  }
  __syncthreads();

  if (tid < 64) {
    float z = 0.f;
    for (int d = 0; d < DR; ++d) z += xsf[tid][d] * WwgF[d];
    gp[tid] = wsc / (1.f + expf(-z));
    float m = -1e30f;
#pragma unroll
    for (int j = 0; j < 16; ++j) m = fmaxf(m, attn[tid][j]);
    float s = 0.f;
#pragma unroll
    for (int j = 0; j < 16; ++j) { float e = expf(attn[tid][j] - m); attn[tid][j] = e; s += e; }
    float inv = 1.f / s;
#pragma unroll
    for (int j = 0; j < 16; ++j) attn[tid][j] *= inv;
  }
  __syncthreads();

  // wv GEMM: wave w -> tokens w*16..+15, all 128 cols
  bfrag a2[4];
#pragma unroll
  for (int kt = 0; kt < 4; ++kt)
    a2[kt] = *(const bfrag*)&xsb[w * 16 + mrow][kt * 32 + quad * 8];

  f32x4 acc[8];
#pragma unroll
  for (int i = 0; i < 8; ++i) acc[i] = (f32x4){0.f, 0.f, 0.f, 0.f};
#pragma unroll
  for (int kt = 0; kt < 4; ++kt)
#pragma unroll
    for (int nt = 0; nt < 8; ++nt) {
      bfrag b = *(const bfrag*)(WwvB + (size_t)(nt * 16 + mrow) * DR + kt * 32 + quad * 8);
      acc[nt] = __builtin_amdgcn_mfma_f32_16x16x32_bf16(a2[kt], b, acc[nt], 0, 0, 0);
    }

  const float c01 = wsc * 0.1f;
#pragma unroll
  for (int nt = 0; nt < 8; ++nt) {
    const int col = nt * 16 + mrow;
#pragma unroll
    for (int r = 0; r < 4; ++r) {
      const int t = w * 16 + quad * 4 + r;
      float mo = 0.f;
#pragma unroll
      for (int j = 0; j < 16; ++j) mo += attn[t][j] * slotsF[j * DR + col];
      float val = xsf[t][col] + gp[t] * acc[nt][r] + c01 * mo;
      RF[(size_t)(t0 + t) * DR + col] = f2b_bits(val);
    }
  }
}

// -------------------- up projection + residual (MFMA) ----------------------
__global__ __launch_bounds__(256) void k_up(const ushort* __restrict__ Rf,
                                            const ushort* __restrict__ WuE,
                                            const float* __restrict__ hidden,
                                            float* __restrict__ out) {
  const int wave = threadIdx.x >> 6, lane = threadIdx.x & 63;
  const int quad = lane >> 4, mrow = lane & 15;
  const int mt = blockIdx.x >> 3, ngrp = blockIdx.x & 7;
  const int m0 = mt * 64 + wave * 16;
  const int ng = ngrp * 8;

  f32x4 acc[8];
#pragma unroll
  for (int i = 0; i < 8; ++i) acc[i] = (f32x4){0.f, 0.f, 0.f, 0.f};

  const ushort* Ap = Rf + (size_t)(m0 + mrow) * DR + quad * 8;
#pragma unroll
  for (int kt = 0; kt < 4; ++kt) {
    bfrag a = *(const bfrag*)(Ap + kt * 32);
#pragma unroll
    for (int nt = 0; nt < 8; ++nt) {
      const ushort* Bp = WuE + (size_t)((ng + nt) * 16 + mrow) * DR + kt * 32 + quad * 8;
      bfrag b = *(const bfrag*)Bp;
      acc[nt] = __builtin_amdgcn_mfma_f32_16x16x32_bf16(a, b, acc[nt], 0, 0, 0);
    }
  }
#pragma unroll
  for (int nt = 0; nt < 8; ++nt)
#pragma unroll
    for (int r = 0; r < 4; ++r) {
      const int token = m0 + quad * 4 + r;
      const int j = (ng + nt) * 16 + mrow;
      const size_t idx = (size_t)token * DM + j;
      out[idx] = hidden[idx] + acc[nt][r];
    }
}

// ---------------------------------------------------------------------------
extern "C" void kernel_launch(void* const* d_in, const int* in_sizes, int n_in,
                              void* d_out, int out_size, void* d_ws, size_t ws_size,
                              hipStream_t stream) {
  int ns[20]; int nn = 0; int lastsc = -1;
  for (int i = 0; i < n_in; ++i) {
    if (in_sizes[i] == 1) lastsc = i;
    else if (nn < 20) ns[nn++] = i;
  }
  int iH = 0, iWd = 2, iWu = 3, iOps = 4, iWr = 5, iSl = 6, iRe = 7,
      iWk = 8, iWg = 9, iWv = 10, iMx = 11, iG = 12, iB = 13;
  if (nn >= 13) {
    iH  = ns[0];  iWd = ns[1];  iWu = ns[2];  iOps = ns[3]; iWr = ns[4];
    iSl = ns[5];  iRe = ns[6];  iWk = ns[7];  iWg = ns[8];  iWv = ns[9];
    iMx = ns[10]; iG  = ns[11]; iB  = ns[12];
  }
  const float* hidden   = (const float*)d_in[iH];
  const float* W_down   = (const float*)d_in[iWd];
  const float* W_up     = (const float*)d_in[iWu];
  const float* opsw     = (const float*)d_in[iOps];
  const float* W_router = (const float*)d_in[iWr];
  const float* slots    = (const float*)d_in[iSl];
  const float* W_read   = (const float*)d_in[iRe];
  const float* W_wk     = (const float*)d_in[iWk];
  const float* W_wg     = (const float*)d_in[iWg];
  const float* W_wv     = (const float*)d_in[iWv];
  const float* W_mix    = (const float*)d_in[iMx];
  const float* lng      = (const float*)d_in[iG];
  const float* lnb      = (const float*)d_in[iB];
  const float* wscale   = (lastsc >= 0) ? (const float*)d_in[lastsc] : (const float*)d_in[iG];
  const int has_wsc     = (lastsc >= 0) ? 1 : 0;

  char* ws = (char*)d_ws;
  float*  sums   = (float*)(ws + OFF_SUMS);
  float*  opsSc  = (float*)(ws + OFF_OPSSC);
  ushort* WdE    = (ushort*)(ws + OFF_WDE);
  ushort* WuE    = (ushort*)(ws + OFF_WUE);
  float*  WrT    = (float*)(ws + OFF_WRT);
  ushort* opsB   = (ushort*)(ws + OFF_OPSB);
  ushort* WmixA  = (ushort*)(ws + OFF_WMIXA);
  ushort* WwvB   = (ushort*)(ws + OFF_WWVB);
  float*  Mrs    = (float*)(ws + OFF_MRS);
  float*  Mws    = (float*)(ws + OFF_MWS);
  float*  SBw    = (float*)(ws + OFF_SB);
  float*  slotsF = (float*)(ws + OFF_SLOTS);
  float*  WwgF   = (float*)(ws + OFF_WWG);
  float*  gammaF = (float*)(ws + OFF_GAMMA);
  float*  betaF  = (float*)(ws + OFF_BETA);
  float*  wscF   = (float*)(ws + OFF_WSC);
  ushort* RF     = (ushort*)(ws + OFF_RF);

  float* X = (float*)d_out;    // fp32 [16384][128] staged in d_out; k_up overwrites

  hipMemsetAsync(ws + OFF_SUMS, 0, 256, stream);
  k_absum<<<128, 256, 0, stream>>>(W_down, 131072, &sums[0]);
  k_absum<<<4, 256, 0, stream>>>(W_router, 4096, &sums[1]);
  k_absum<<<128, 256, 0, stream>>>(W_up, 131072, &sums[2]);
  k_absum_ops<<<dim3(4, 32), 256, 0, stream>>>(opsw, sums + 3);
  k_build<<<3250, 256, 0, stream>>>(W_down, W_up, W_router, opsw, W_read, W_wk, W_wg,
                                    W_wv, W_mix, slots, lng, lnb, wscale, has_wsc,
                                    sums, WdE, WuE, WrT, opsB, opsSc, WmixA, WwvB,
                                    Mrs, Mws, SBw, slotsF, WwgF, gammaF, betaF, wscF);
  k_down<<<512, 256, 0, stream>>>(hidden, WdE, X);
  for (int pass = 0; pass < 2; ++pass)
    k_pass2<<<256, 512, 0, stream>>>(X, WrT, opsB, opsSc, WmixA, Mrs, SBw,
                                     gammaF, betaF);
  k_wsig<<<256, 256, 0, stream>>>(X, RF, WwvB, Mws, slotsF, WwgF, wscF);
  k_up<<<2048, 256, 0, stream>>>(RF, WuE, hidden, X);
}